// Round 1
// baseline (662.302 us; speedup 1.0000x reference)
//
#include <hip/hip_runtime.h>

// GCN forward on MI355X — bf16 intermediate pipeline.
//
// CSR build: per-workgroup bucket hist -> flat scan -> partition-private
// scatter -> per-bucket finalize (exclusive 64B-line ownership per writer).
//
// R5: (1) SpMM rewritten wave-per-row: edge descriptors fetched once per
// wave and broadcast via v_readlane (VALU) instead of ds_bpermute (lgkm);
// 16 gathers in flight/wave, scalar saddr addressing. (2) bucket_to_csr
// fused with gemm1 (independent: memory/atomic-bound vs MFMA-bound),
// prep_w1 fused with hist; make_bstart deleted (bucket reads off[] direct).
// support1 de-unioned from bcolval to make the fusion race-free (ws ~800MB).

#define NN 100000
#define NE 3200000
#define FIN 512
#define FHID 128
#define FOUT 32
#define BROWS 256          // rows per bucket
#define NBUCK 391          // ceil(NN/256)
#define NPART 256          // scatter partitions (workgroups)
#define CHUNK 12800        // edges per partition; NPART*CHUNK >= NE
#define TOT (NBUCK * NPART)  // 100096 counter cells
#define NSCAN1 98          // ceil(TOT/1024)
#define GG1 ((NN + 127) / 128)  // gemm1 blocks = 782

typedef __attribute__((ext_vector_type(8))) short bf16x8;
typedef __attribute__((ext_vector_type(4))) float f32x4;

static __device__ __forceinline__ unsigned short f2bf(float f) {
    unsigned u = __float_as_uint(f);
    unsigned r = (u + 0x7FFFu + ((u >> 16) & 1u)) >> 16;  // RTN-even
    return (unsigned short)r;
}
static __device__ __forceinline__ float bf2f(unsigned short u) {
    return __uint_as_float(((unsigned)u) << 16);
}
static __device__ __forceinline__ float bflo(unsigned u) {
    return __uint_as_float(u << 16);
}
static __device__ __forceinline__ float bfhi(unsigned u) {
    return __uint_as_float(u & 0xffff0000u);
}

// ---------------- CSR build phase 1: hist (+ fused W1 transpose) ----------------
__global__ __launch_bounds__(256) void fused_prep_hist(const float* __restrict__ W1,
                                                       unsigned short* __restrict__ W1t,
                                                       const int* __restrict__ erow,
                                                       int* __restrict__ cntG) {
    if (blockIdx.x < NPART) {
        __shared__ int c[NBUCK];
        const int t = threadIdx.x;
        const int w = blockIdx.x;
        for (int i = t; i < NBUCK; i += 256) c[i] = 0;
        __syncthreads();
        const int e0 = w * CHUNK;
        const int e1 = min(e0 + CHUNK, NE);
        for (int e = e0 + t; e < e1; e += 256) atomicAdd(&c[erow[e] >> 8], 1);
        __syncthreads();
        for (int i = t; i < NBUCK; i += 256) cntG[w * NBUCK + i] = c[i];
    } else {
        int t = (blockIdx.x - NPART) * 256 + threadIdx.x;
        int n = t & 127;
        int k = t >> 7;
        W1t[n * 512 + k] = f2bf(W1[k * 128 + n]);
    }
}

__global__ __launch_bounds__(256) void scan1_kernel(const int* __restrict__ cntG,
                                                    int* __restrict__ off,
                                                    int* __restrict__ partials) {
    __shared__ int s[256];
    int t = threadIdx.x;
    int i0 = blockIdx.x * 1024 + t * 4;
    int v[4];
#pragma unroll
    for (int j = 0; j < 4; ++j) {
        int i = i0 + j;
        v[j] = (i < TOT) ? cntG[(i & (NPART - 1)) * NBUCK + (i >> 8)] : 0;
    }
    int lsum = v[0] + v[1] + v[2] + v[3];
    s[t] = lsum;
    __syncthreads();
    for (int o = 1; o < 256; o <<= 1) {
        int xv = (t >= o) ? s[t - o] : 0;
        __syncthreads();
        s[t] += xv;
        __syncthreads();
    }
    if (t == 255) partials[blockIdx.x] = s[255];
    int run = s[t] - lsum;
#pragma unroll
    for (int j = 0; j < 4; ++j) {
        if (i0 + j < TOT) off[i0 + j] = run;
        run += v[j];
    }
}

__global__ void scan2_kernel(int* partials) {
    __shared__ int s[128];
    int t = threadIdx.x;
    int v = (t < NSCAN1) ? partials[t] : 0;
    s[t] = v;
    __syncthreads();
    for (int o = 1; o < 128; o <<= 1) {
        int xv = (t >= o) ? s[t - o] : 0;
        __syncthreads();
        s[t] += xv;
        __syncthreads();
    }
    if (t < NSCAN1) partials[t] = s[t] - v;
}

__global__ __launch_bounds__(256) void scan3_kernel(int* __restrict__ off,
                                                    const int* __restrict__ partials) {
    int add = partials[blockIdx.x];
    int i0 = blockIdx.x * 1024 + threadIdx.x * 4;
#pragma unroll
    for (int j = 0; j < 4; ++j)
        if (i0 + j < TOT) off[i0 + j] += add;
}

__global__ __launch_bounds__(256) void scatter_part(const int* __restrict__ erow,
                                                    const int* __restrict__ ecol,
                                                    const float* __restrict__ eval,
                                                    const int* __restrict__ off,
                                                    int2* __restrict__ bcolval) {
    __shared__ int pos[NBUCK];
    const int t = threadIdx.x;
    const int w = blockIdx.x;
    for (int b = t; b < NBUCK; b += 256) pos[b] = off[b * NPART + w];
    __syncthreads();
    const int e0 = w * CHUNK;
    const int e1 = min(e0 + CHUNK, NE);
    for (int e = e0 + t; e < e1; e += 256) {
        int r = erow[e];
        int idx = atomicAdd(&pos[r >> 8], 1);
        bcolval[idx] = make_int2(ecol[e] | ((r & 255) << 20), __float_as_int(eval[e]));
    }
}

// ---------------- Fused: gemm1 (MFMA) || bucket_to_csr ----------------
// Independent work: gemm1 is MFMA/x-stream-bound, bucket finalize is
// LDS-atomic/scatter-bound — complementary pipes, overlap on the grid.
__global__ __launch_bounds__(256) void fused_csr_gemm1(
    const int* __restrict__ off, const int2* __restrict__ bcolval,
    int* __restrict__ rowptr, int2* __restrict__ epack,
    const float* __restrict__ x, const unsigned short* __restrict__ W1t,
    unsigned short* __restrict__ outd) {
    if (blockIdx.x < GG1) {
        // ---- gemm1: support1(bf16) = x(f32) @ W1 ----
        __shared__ __align__(16) unsigned short As[128 * 32];
        const int tid = threadIdx.x;
        const int lane = tid & 63;
        const int w = __builtin_amdgcn_readfirstlane(tid >> 6);
        const int quad = lane >> 4;
        const int m = lane & 15;
        const int row0 = blockIdx.x * 128;

        f32x4 acc[8][2];
#pragma unroll
        for (int mt = 0; mt < 8; ++mt)
#pragma unroll
            for (int nt = 0; nt < 2; ++nt) acc[mt][nt] = (f32x4){0.f, 0.f, 0.f, 0.f};

        int srow[4], skq[4];
        const float* sptr[4];
#pragma unroll
        for (int s = 0; s < 4; ++s) {
            int f = tid + s * 256;
            srow[s] = f >> 3;
            skq[s] = f & 7;
            sptr[s] = x + (size_t)(row0 + srow[s]) * FIN + skq[s] * 4;
        }
        float4 ld[4];
#pragma unroll
        for (int s = 0; s < 4; ++s)
            ld[s] = (row0 + srow[s] < NN) ? *(const float4*)sptr[s]
                                          : make_float4(0.f, 0.f, 0.f, 0.f);

        for (int ks = 0; ks < 16; ++ks) {
            __syncthreads();
#pragma unroll
            for (int s = 0; s < 4; ++s) {
                int r = srow[s], kq = skq[s];
                int mt = r >> 4, mm = r & 15;
                int offs = mt * 512 + (kq >> 1) * 128 + mm * 8 + (kq & 1) * 4;
                ushort4 p;
                p.x = f2bf(ld[s].x);
                p.y = f2bf(ld[s].y);
                p.z = f2bf(ld[s].z);
                p.w = f2bf(ld[s].w);
                *(ushort4*)&As[offs] = p;
            }
            __syncthreads();
            if (ks < 15) {
#pragma unroll
                for (int s = 0; s < 4; ++s)
                    ld[s] = (row0 + srow[s] < NN)
                                ? *(const float4*)(sptr[s] + (ks + 1) * 32)
                                : make_float4(0.f, 0.f, 0.f, 0.f);
            }
            bf16x8 bfr[2];
#pragma unroll
            for (int nt = 0; nt < 2; ++nt) {
                int n = (w * 2 + nt) * 16 + m;
                bfr[nt] = *(const bf16x8*)(W1t + (size_t)n * 512 + ks * 32 + quad * 8);
            }
#pragma unroll
            for (int mt = 0; mt < 8; ++mt) {
                bf16x8 af = *(const bf16x8*)&As[mt * 512 + quad * 128 + m * 8];
                acc[mt][0] = __builtin_amdgcn_mfma_f32_16x16x32_bf16(af, bfr[0], acc[mt][0], 0, 0, 0);
                acc[mt][1] = __builtin_amdgcn_mfma_f32_16x16x32_bf16(af, bfr[1], acc[mt][1], 0, 0, 0);
            }
        }
#pragma unroll
        for (int mt = 0; mt < 8; ++mt)
#pragma unroll
            for (int nt = 0; nt < 2; ++nt) {
                int col = (w * 2 + nt) * 16 + m;
#pragma unroll
                for (int r = 0; r < 4; ++r) {
                    int row = row0 + mt * 16 + quad * 4 + r;
                    if (row < NN) outd[(size_t)row * FHID + col] = f2bf(acc[mt][nt][r]);
                }
            }
    } else {
        // ---- bucket_to_csr ----
        __shared__ int cnt[256];
        __shared__ int pos[256];
        __shared__ int s[256];
        const int b = blockIdx.x - GG1;
        const int t = threadIdx.x;
        const int s0 = off[b * NPART];
        const int send = (b == NBUCK - 1) ? NE : off[(b + 1) * NPART];
        const int n = send - s0;
        cnt[t] = 0;
        __syncthreads();
        for (int i = t; i < n; i += 256)
            atomicAdd(&cnt[((unsigned)bcolval[s0 + i].x) >> 20], 1);
        __syncthreads();
        int myc = cnt[t];
        s[t] = myc;
        __syncthreads();
        for (int o = 1; o < 256; o <<= 1) {
            int xv = (t >= o) ? s[t - o] : 0;
            __syncthreads();
            s[t] += xv;
            __syncthreads();
        }
        int excl = s[t] - myc;
        pos[t] = excl;
        int row = b * BROWS + t;
        if (row < NN) rowptr[row] = s0 + excl;
        if (b == 0 && t == 0) rowptr[NN] = NE;
        __syncthreads();
        for (int i = t; i < n; i += 256) {
            int2 v = bcolval[s0 + i];
            int p = atomicAdd(&pos[((unsigned)v.x) >> 20], 1);
            epack[s0 + p] = make_int2(v.x & 0xFFFFF, v.y);
        }
    }
}

// ---------------- SpMM1 + bias + relu: h(bf16) = relu(A @ support1 + b1) ----------------
// Wave-per-row: lane covers cols (2*lane, 2*lane+1) -> 4B gather/lane,
// 256B/edge contiguous. Edge descriptors wave-uniform: fetched once
// (lanes 0..15 hold 16 descs) and broadcast via v_readlane (VALU, no
// bpermute/lgkm). 16 saddr-form gathers in flight per wave.
__global__ __launch_bounds__(256) void spmm1_kernel(const int* __restrict__ rowptr,
                                                    const int2* __restrict__ epack,
                                                    const unsigned short* __restrict__ dense,
                                                    const float* __restrict__ b1,
                                                    unsigned short* __restrict__ h) {
    const int lane = threadIdx.x & 63;
    const int row = blockIdx.x * 4 + (threadIdx.x >> 6);
    const int start = __builtin_amdgcn_readfirstlane(rowptr[row]);
    const int cnt = __builtin_amdgcn_readfirstlane(rowptr[row + 1]) - start;
    const int sl16 = lane & 15;
    float acc0 = 0.f, acc1 = 0.f;

    for (int j = 0; j < cnt; j += 16) {
        int idx = j + sl16;
        idx = idx < cnt ? idx : cnt - 1;  // clamp: tail lanes re-read last desc
        const int2 p = epack[start + idx];
        const int rem = cnt - j;
        unsigned d[16];
#pragma unroll
        for (int k = 0; k < 16; ++k) {
            int col = __builtin_amdgcn_readlane(p.x, k);
            col = (k < rem) ? col : 0;  // tail: gather hot line 0, val=0 below
            d[k] = *((const unsigned*)(dense + ((size_t)col << 7)) + lane);
        }
#pragma unroll
        for (int k = 0; k < 16; ++k) {
            float v = (k < rem) ? __int_as_float(__builtin_amdgcn_readlane(p.y, k)) : 0.f;
            acc0 = fmaf(v, bflo(d[k]), acc0);
            acc1 = fmaf(v, bfhi(d[k]), acc1);
        }
    }
    float2 bb = *(const float2*)(b1 + lane * 2);
    unsigned r0 = f2bf(fmaxf(acc0 + bb.x, 0.f));
    unsigned r1 = f2bf(fmaxf(acc1 + bb.y, 0.f));
    *((unsigned*)(h + (size_t)row * FHID) + lane) = r0 | (r1 << 16);
}

// ---------------- GEMM2: support2(bf16) = h(bf16) @ W2(f32) ----------------
__global__ __launch_bounds__(256) void gemm2_kernel(const unsigned short* __restrict__ h,
                                                    const float* __restrict__ W2,
                                                    unsigned short* __restrict__ out) {
    __shared__ float hs[64][129];
    const int tid = threadIdx.x;
    const int lane = tid & 63;
    const int cg = __builtin_amdgcn_readfirstlane(tid >> 6);
    const int row0 = blockIdx.x * 64;
    const int row = row0 + lane;

    float acc[8];
#pragma unroll
    for (int c = 0; c < 8; ++c) acc[c] = 0.f;

#pragma unroll
    for (int j = 0; j < 8; ++j) {
        int f4 = tid + j * 256;
        int r = f4 >> 5;
        int kq = f4 & 31;
        ushort4 v = make_ushort4(0, 0, 0, 0);
        if (row0 + r < NN) v = *(const ushort4*)(h + (size_t)(row0 + r) * FHID + kq * 4);
        hs[r][kq * 4 + 0] = bf2f(v.x);
        hs[r][kq * 4 + 1] = bf2f(v.y);
        hs[r][kq * 4 + 2] = bf2f(v.z);
        hs[r][kq * 4 + 3] = bf2f(v.w);
    }
    __syncthreads();
#pragma unroll 4
    for (int k = 0; k < FHID; ++k) {
        float a = hs[lane][k];
        const float* wrow = W2 + k * FOUT + cg * 8;
#pragma unroll
        for (int c = 0; c < 8; ++c) acc[c] += a * wrow[c];
    }
    if (row < NN) {
        uint4 st;
        st.x = (unsigned)f2bf(acc[0]) | ((unsigned)f2bf(acc[1]) << 16);
        st.y = (unsigned)f2bf(acc[2]) | ((unsigned)f2bf(acc[3]) << 16);
        st.z = (unsigned)f2bf(acc[4]) | ((unsigned)f2bf(acc[5]) << 16);
        st.w = (unsigned)f2bf(acc[6]) | ((unsigned)f2bf(acc[7]) << 16);
        *(uint4*)(out + (size_t)row * FOUT + cg * 8) = st;
    }
}

// ------- SpMM2 + bias + log_softmax (fp32 out) -------
// Wave-per-row, lane owns col (lane&31), half-waves process 2 edges/step
// (slot = lane>>5). Descs wave-uniform via v_readlane; 8 gathers in flight.
__global__ __launch_bounds__(256) void spmm2_kernel(const int* __restrict__ rowptr,
                                                    const int2* __restrict__ epack,
                                                    const unsigned short* __restrict__ dense,
                                                    const float* __restrict__ b2,
                                                    float* __restrict__ out) {
    const int lane = threadIdx.x & 63;
    const int row = blockIdx.x * 4 + (threadIdx.x >> 6);
    const int start = __builtin_amdgcn_readfirstlane(rowptr[row]);
    const int cnt = __builtin_amdgcn_readfirstlane(rowptr[row + 1]) - start;
    const int col = lane & 31;
    const int slot = lane >> 5;
    const int sl16 = lane & 15;
    float acc = 0.f;

    for (int j = 0; j < cnt; j += 16) {
        int idx = j + sl16;
        idx = idx < cnt ? idx : cnt - 1;
        const int2 p = epack[start + idx];
        const int rem = cnt - j;
        unsigned short d[8];
        float vv[8];
#pragma unroll
        for (int k = 0; k < 8; ++k) {
            int cA = __builtin_amdgcn_readlane(p.x, 2 * k);
            int cB = __builtin_amdgcn_readlane(p.x, 2 * k + 1);
            int ei = 2 * k + slot;
            int c = slot ? cB : cA;
            c = (ei < rem) ? c : 0;
            d[k] = *(dense + (size_t)c * FOUT + col);
            int vA = __builtin_amdgcn_readlane(p.y, 2 * k);
            int vB = __builtin_amdgcn_readlane(p.y, 2 * k + 1);
            float v = __int_as_float(slot ? vB : vA);
            vv[k] = (ei < rem) ? v : 0.f;
        }
#pragma unroll
        for (int k = 0; k < 8; ++k) acc = fmaf(vv[k], bf2f(d[k]), acc);
    }
    acc += __shfl_xor(acc, 32, 64);  // combine the two edge-slots per col
    acc += b2[col];
    float m = acc;
#pragma unroll
    for (int mask = 16; mask >= 1; mask >>= 1) m = fmaxf(m, __shfl_xor(m, mask, 64));
    float ex = expf(acc - m);
    float ssum = ex;
#pragma unroll
    for (int mask = 16; mask >= 1; mask >>= 1) ssum += __shfl_xor(ssum, mask, 64);
    float lse = m + logf(ssum);
    if (lane < 32) out[(size_t)row * FOUT + col] = acc - lse;
}

extern "C" void kernel_launch(void* const* d_in, const int* in_sizes, int n_in,
                              void* d_out, int out_size, void* d_ws, size_t ws_size,
                              hipStream_t stream) {
    const float* x = (const float*)d_in[0];
    const int* erow = (const int*)d_in[1];
    const int* ecol = (const int*)d_in[2];
    const float* eval = (const float*)d_in[3];
    const float* W1 = (const float*)d_in[4];
    const float* b1 = (const float*)d_in[5];
    const float* W2 = (const float*)d_in[6];
    const float* b2 = (const float*)d_in[7];
    float* out = (float*)d_out;

    char* ws = (char*)d_ws;
    size_t off_b = 0;
    auto walloc = [&](size_t bytes) -> void* {
        void* p = ws + off_b;
        off_b = (off_b + bytes + 255) & ~(size_t)255;
        return p;
    };
    int2* epack = (int2*)walloc((size_t)NE * 8);
    int* rowptr = (int*)walloc((size_t)(NN + 1) * 4);
    int* cntG = (int*)walloc((size_t)TOT * 4);
    int* off = (int*)walloc((size_t)TOT * 4);
    int* partials = (int*)walloc(4096);
    unsigned short* W1t = (unsigned short*)walloc((size_t)FHID * FIN * 2);
    // de-unioned: bucket_to_csr reads bcolval WHILE gemm1 writes support1
    int2* bcolval = (int2*)walloc((size_t)NE * 8);
    unsigned short* support1 = (unsigned short*)walloc((size_t)NN * FHID * 2);
    unsigned short* h = (unsigned short*)walloc((size_t)NN * FHID * 2);
    unsigned short* support2 = support1;  // support1 dead after spmm1

    fused_prep_hist<<<NPART + 256, 256, 0, stream>>>(W1, W1t, erow, cntG);
    scan1_kernel<<<NSCAN1, 256, 0, stream>>>(cntG, off, partials);
    scan2_kernel<<<1, 128, 0, stream>>>(partials);
    scan3_kernel<<<NSCAN1, 256, 0, stream>>>(off, partials);
    scatter_part<<<NPART, 256, 0, stream>>>(erow, ecol, eval, off, bcolval);
    fused_csr_gemm1<<<GG1 + NBUCK, 256, 0, stream>>>(off, bcolval, rowptr, epack,
                                                     x, W1t, support1);
    spmm1_kernel<<<NN / 4, 256, 0, stream>>>(rowptr, epack, support1, b1, h);
    gemm2_kernel<<<(NN + 63) / 64, 256, 0, stream>>>(h, W2, support2);
    spmm2_kernel<<<NN / 4, 256, 0, stream>>>(rowptr, epack, support2, b2, out);
}